// Round 1
// baseline (164.099 us; speedup 1.0000x reference)
//
#include <hip/hip_runtime.h>
#include <hip/hip_bf16.h>

#define N_CURR 4096
#define M_PREV 10240
#define DIM 256
#define BM 128
#define BN 128
#define BK 32
#define NBX (M_PREV / BN)   // 80
#define NBY (N_CURR / BM)   // 32
#define NBLK (NBX * NBY)    // 2560

typedef short short8 __attribute__((ext_vector_type(8)));
typedef float f32x4 __attribute__((ext_vector_type(4)));

__device__ __forceinline__ unsigned short f2bf(float f) {
  union { float f; unsigned int u; } x; x.f = f;
  unsigned int u = x.u;
  return (unsigned short)((u + 0x7fffu + ((u >> 16) & 1u)) >> 16);  // RNE
}

__device__ __forceinline__ void async16(const void* g, void* l) {
  __builtin_amdgcn_global_load_lds(
      (const __attribute__((address_space(1))) unsigned int*)g,
      (__attribute__((address_space(3))) unsigned int*)l, 16, 0, 0);
}

// One wave per row: squared norm, inv-norm, bf16 cast, centers.
__global__ __launch_bounds__(256) void prep_kernel(
    const float* __restrict__ ce, const float* __restrict__ cbx,
    const float* __restrict__ pe, const float* __restrict__ pbx,
    ushort* __restrict__ cbf, ushort* __restrict__ pbf,
    float* __restrict__ c2, float* __restrict__ invnc,
    float* __restrict__ ccx, float* __restrict__ ccy,
    float* __restrict__ p2, float* __restrict__ invnp,
    float* __restrict__ pcx, float* __restrict__ pcy)
{
  int gw = (blockIdx.x * 256 + threadIdx.x) >> 6;   // global wave = row
  int lane = threadIdx.x & 63;
  bool isCurr = gw < N_CURR;
  int row = isCurr ? gw : gw - N_CURR;
  const float* src = (isCurr ? ce : pe) + (size_t)row * DIM;
  ushort* dst = (isCurr ? cbf : pbf) + (size_t)row * DIM;

  float4 v = ((const float4*)src)[lane];            // 64 lanes x 16B = full row
  ushort4 b;
  b.x = f2bf(v.x); b.y = f2bf(v.y); b.z = f2bf(v.z); b.w = f2bf(v.w);
  ((ushort4*)dst)[lane] = b;

  float s = v.x*v.x + v.y*v.y + v.z*v.z + v.w*v.w;
  #pragma unroll
  for (int m = 32; m; m >>= 1) s += __shfl_xor(s, m);

  if (lane == 0) {
    float nrm = fmaxf(sqrtf(s), 1e-12f);
    if (isCurr) {
      c2[row] = s; invnc[row] = 1.0f / nrm;
      float4 bb = ((const float4*)cbx)[row];
      ccx[row] = bb.x + 0.5f * bb.z;
      ccy[row] = bb.y + 0.5f * bb.w;
    } else {
      p2[row] = s; invnp[row] = 1.0f / nrm;
      float4 bb = ((const float4*)pbx)[row];
      pcx[row] = bb.x + 0.5f * bb.z;
      pcy[row] = bb.y + 0.5f * bb.w;
    }
  }
}

// 128x128 tile NT-GEMM (dot = curr . prev) + fused epilogue.
__global__ __launch_bounds__(256) void main_kernel(
    const ushort* __restrict__ cbf, const ushort* __restrict__ pbf,
    const float* __restrict__ c2, const float* __restrict__ invnc,
    const float* __restrict__ ccx, const float* __restrict__ ccy,
    const float* __restrict__ p2, const float* __restrict__ invnp,
    const float* __restrict__ pcx, const float* __restrict__ pcy,
    const int* __restrict__ cid, const int* __restrict__ pid,
    float* __restrict__ out, float* __restrict__ partials)
{
  __shared__ __align__(16) ushort Al[2][BM][BK];   // 16 KB
  __shared__ __align__(16) ushort Bl[2][BN][BK];   // 16 KB
  __shared__ float rowp[4][BM];                    // invnc, c2, ccx, ccy
  __shared__ float colp[4][BN];                    // invnp, p2, pcx, pcy
  __shared__ int ridl[BM];
  __shared__ int cidl[BN];
  __shared__ float wsum[4];

  const int bid = blockIdx.x;
  const int bx = bid % NBX;
  const int by = bid / NBX;
  const int r0 = by * BM;
  const int c0 = bx * BN;
  const int tid = threadIdx.x;
  const int lane = tid & 63;
  const int wid = tid >> 6;

  // Stage per-row / per-col params into LDS (covered by first loop barrier).
  if (tid < BM) {
    int i = r0 + tid;
    rowp[0][tid] = invnc[i]; rowp[1][tid] = c2[i];
    rowp[2][tid] = ccx[i];   rowp[3][tid] = ccy[i];
    ridl[tid] = cid[i];
  } else {
    int t = tid - BM;
    int j = c0 + t;
    colp[0][t] = invnp[j]; colp[1][t] = p2[j];
    colp[2][t] = pcx[j];   colp[3][t] = pcy[j];
    cidl[t] = pid[j];
  }

  const int lrow = lane >> 2;        // 0..15 within 16-row chunk
  const int lk   = (lane & 3) * 8;   // bf16 col offset

  // Each wave stages 32 rows of A and of B per K-step (2x 1KB chunks each).
  auto stage = [&](int buf, int ks) {
    int k0 = ks * BK;
    int t0 = wid * 2;  // chunk index, chunk = 16 rows
    const ushort* gA = cbf + (size_t)(r0 + t0*16 + lrow) * DIM + k0 + lk;
    async16(gA,            &Al[buf][t0*16][0]);
    async16(gA + 16*DIM,   &Al[buf][t0*16 + 16][0]);
    const ushort* gB = pbf + (size_t)(c0 + t0*16 + lrow) * DIM + k0 + lk;
    async16(gB,            &Bl[buf][t0*16][0]);
    async16(gB + 16*DIM,   &Bl[buf][t0*16 + 16][0]);
  };

  f32x4 acc[4][4];
  #pragma unroll
  for (int m = 0; m < 4; ++m)
    #pragma unroll
    for (int n = 0; n < 4; ++n)
      acc[m][n] = (f32x4){0.f, 0.f, 0.f, 0.f};

  const int wr = wid >> 1, wc = wid & 1;   // 2x2 wave grid, 64x64 per wave
  const int rb = wr * 64, cbase = wc * 64;
  const int frow = lane & 15;
  const int fk = (lane >> 4) * 8;

  stage(0, 0);
  #pragma unroll
  for (int ks = 0; ks < DIM / BK; ++ks) {
    __syncthreads();                       // staged tile ks is ready
    if (ks < DIM / BK - 1) stage((ks + 1) & 1, ks + 1);
    int buf = ks & 1;
    short8 af[4], bfr[4];
    #pragma unroll
    for (int m = 0; m < 4; ++m)
      af[m] = *(const short8*)&Al[buf][rb + m*16 + frow][fk];
    #pragma unroll
    for (int n = 0; n < 4; ++n)
      bfr[n] = *(const short8*)&Bl[buf][cbase + n*16 + frow][fk];
    #pragma unroll
    for (int m = 0; m < 4; ++m)
      #pragma unroll
      for (int n = 0; n < 4; ++n)
        acc[m][n] = __builtin_amdgcn_mfma_f32_16x16x32_bf16(af[m], bfr[n], acc[m][n], 0, 0, 0);
  }

  // Epilogue: C/D layout col = lane&15, row = (lane>>4)*4 + reg.
  float lp = 0.f;
  #pragma unroll
  for (int n = 0; n < 4; ++n) {
    int jl = cbase + n*16 + frow;
    int j = c0 + jl;
    float inp = colp[0][jl], pp2 = colp[1][jl];
    float px = colp[2][jl], py = colp[3][jl];
    int pj = cidl[jl];
    #pragma unroll
    for (int m = 0; m < 4; ++m) {
      int il0 = rb + m*16 + (lane >> 4) * 4;
      #pragma unroll
      for (int r = 0; r < 4; ++r) {
        int il = il0 + r;
        float dot = acc[m][n][r];
        float cs = 1.0f - dot * rowp[0][il] * inp;
        float dx = rowp[2][il] - px;
        float dy = rowp[3][il] - py;
        float ccd = sqrtf(dx*dx + dy*dy);
        out[(size_t)(r0 + il) * M_PREV + j] = 0.7f * cs + 0.3f * ccd;
        float d2 = fmaxf(rowp[1][il] + pp2 - 2.0f * dot, 0.0f);
        float dist = sqrtf(d2);
        float tt = fmaxf(1.0f - dist, 0.0f);
        lp += (ridl[il] == pj) ? d2 : tt * tt;
      }
    }
  }

  #pragma unroll
  for (int m = 32; m; m >>= 1) lp += __shfl_xor(lp, m);
  if (lane == 0) wsum[wid] = lp;
  __syncthreads();
  if (tid == 0) partials[bid] = (wsum[0] + wsum[1]) + (wsum[2] + wsum[3]);
}

// Deterministic fixed-order reduction of block partials.
__global__ __launch_bounds__(256) void finalize_loss(
    const float* __restrict__ partials, float* __restrict__ loss_out)
{
  __shared__ float sh[4];
  float s = 0.f;
  for (int i = threadIdx.x; i < NBLK; i += 256) s += partials[i];
  #pragma unroll
  for (int m = 32; m; m >>= 1) s += __shfl_xor(s, m);
  if ((threadIdx.x & 63) == 0) sh[threadIdx.x >> 6] = s;
  __syncthreads();
  if (threadIdx.x == 0)
    loss_out[0] = ((sh[0] + sh[1]) + (sh[2] + sh[3])) * (1.0f / 41943040.0f);
}

extern "C" void kernel_launch(void* const* d_in, const int* in_sizes, int n_in,
                              void* d_out, int out_size, void* d_ws, size_t ws_size,
                              hipStream_t stream) {
  const float* ce  = (const float*)d_in[0];
  const float* cbx = (const float*)d_in[1];
  const float* pe  = (const float*)d_in[2];
  const float* pbx = (const float*)d_in[3];
  const int*   cid = (const int*)d_in[4];
  const int*   pid = (const int*)d_in[5];
  float* out = (float*)d_out;

  char* ws = (char*)d_ws;
  ushort* cbf = (ushort*)ws;                       // 4096*256*2  = 2 MB
  ushort* pbf = (ushort*)(ws + 2097152);           // 10240*256*2 = 5 MB
  float* fb    = (float*)(ws + 7340032);
  float* c2    = fb;
  float* invnc = fb + 4096;
  float* ccx   = fb + 8192;
  float* ccy   = fb + 12288;
  float* p2    = fb + 16384;
  float* invnp = p2 + 10240;
  float* pcx   = invnp + 10240;
  float* pcy   = pcx + 10240;
  float* partials = pcy + 10240;                   // 2560 floats

  prep_kernel<<<(N_CURR + M_PREV) / 4, 256, 0, stream>>>(
      ce, cbx, pe, pbx, cbf, pbf, c2, invnc, ccx, ccy, p2, invnp, pcx, pcy);
  main_kernel<<<NBLK, 256, 0, stream>>>(
      cbf, pbf, c2, invnc, ccx, ccy, p2, invnp, pcx, pcy, cid, pid,
      out, partials);
  finalize_loss<<<1, 256, 0, stream>>>(partials, out + (size_t)N_CURR * M_PREV);
}

// Round 2
// 76.402 us; speedup vs baseline: 2.1478x; 2.1478x over previous
//
#include <hip/hip_runtime.h>
#include <hip/hip_bf16.h>

#define N_CURR 4096
#define M_PREV 10240
#define DIM 256
#define BM 128
#define BN 128
#define BK 32
#define NBX (M_PREV / BN)   // 80
#define NBY (N_CURR / BM)   // 32
#define NBLK (NBX * NBY)    // 2560

typedef short short8 __attribute__((ext_vector_type(8)));
typedef float f32x4 __attribute__((ext_vector_type(4)));

__device__ __forceinline__ unsigned short f2bf(float f) {
  union { float f; unsigned int u; } x; x.f = f;
  unsigned int u = x.u;
  return (unsigned short)((u + 0x7fffu + ((u >> 16) & 1u)) >> 16);  // RNE
}

__device__ __forceinline__ void async16(const void* g, void* l) {
  __builtin_amdgcn_global_load_lds(
      (const __attribute__((address_space(1))) unsigned int*)g,
      (__attribute__((address_space(3))) unsigned int*)l, 16, 0, 0);
}

// One wave per row: squared norm, inv-norm, bf16 cast, centers.
// Packs {invn, |x|^2, cx, cy} into one float4 per row.
__global__ __launch_bounds__(256) void prep_kernel(
    const float* __restrict__ ce, const float* __restrict__ cbx,
    const float* __restrict__ pe, const float* __restrict__ pbx,
    ushort* __restrict__ cbf, ushort* __restrict__ pbf,
    float4* __restrict__ cpar, float4* __restrict__ ppar)
{
  int gw = (blockIdx.x * 256 + threadIdx.x) >> 6;   // global wave = row
  int lane = threadIdx.x & 63;
  bool isCurr = gw < N_CURR;
  int row = isCurr ? gw : gw - N_CURR;
  const float* src = (isCurr ? ce : pe) + (size_t)row * DIM;
  ushort* dst = (isCurr ? cbf : pbf) + (size_t)row * DIM;

  float4 v = ((const float4*)src)[lane];            // 64 lanes x 16B = full row
  ushort4 b;
  b.x = f2bf(v.x); b.y = f2bf(v.y); b.z = f2bf(v.z); b.w = f2bf(v.w);
  ((ushort4*)dst)[lane] = b;

  float s = v.x*v.x + v.y*v.y + v.z*v.z + v.w*v.w;
  #pragma unroll
  for (int m = 32; m; m >>= 1) s += __shfl_xor(s, m);

  if (lane == 0) {
    float nrm = fmaxf(__builtin_amdgcn_sqrtf(s), 1e-12f);
    float4 bb = ((const float4*)(isCurr ? cbx : pbx))[row];
    float4 par;
    par.x = 1.0f / nrm;           // inv norm
    par.y = s;                    // squared norm
    par.z = bb.x + 0.5f * bb.z;   // center x
    par.w = bb.y + 0.5f * bb.w;   // center y
    (isCurr ? cpar : ppar)[row] = par;
  }
}

// 128x128 tile NT-GEMM (dot = curr . prev) + fused epilogue.
// MFMA operands SWAPPED (A=prev, B=curr) so each lane's 4 accumulator regs
// hold 4 consecutive prev-columns -> float4 stores.
__global__ __launch_bounds__(256) void main_kernel(
    const ushort* __restrict__ cbf, const ushort* __restrict__ pbf,
    const float4* __restrict__ cpar, const float4* __restrict__ ppar,
    const int* __restrict__ cid, const int* __restrict__ pid,
    float* __restrict__ out, float* __restrict__ partials)
{
  __shared__ __align__(16) ushort Al[2][BM][BK];   // 16 KB
  __shared__ __align__(16) ushort Bl[2][BN][BK];   // 16 KB
  __shared__ float4 rowv[BM];                      // {invnc, c2, cx, cy}
  __shared__ float4 colv[BN];                      // {invnp, p2, px, py}
  __shared__ int ridl[BM];
  __shared__ int cidl[BN];
  __shared__ float wsum[4];

  const int bid = blockIdx.x;
  const int bx = bid % NBX;
  const int by = bid / NBX;
  const int r0 = by * BM;
  const int c0 = bx * BN;
  const int tid = threadIdx.x;
  const int lane = tid & 63;
  const int wid = tid >> 6;

  // Stage per-row / per-col params into LDS (covered by first loop barrier).
  if (tid < BM) {
    rowv[tid] = cpar[r0 + tid];
    ridl[tid] = cid[r0 + tid];
  } else {
    int t = tid - BM;
    colv[t] = ppar[c0 + t];
    cidl[t] = pid[c0 + t];
  }

  const int lrow = lane >> 2;                       // 0..15 row within chunk
  // Source-side XOR swizzle (chunk ^= (row>>1)&3) so LDS reads are 2-way max.
  const int lk = (((lane & 3) ^ ((lrow >> 1) & 3)) * 8);

  // Each wave stages 32 rows of A and of B per K-step (2x 1KB chunks each).
  auto stage = [&](int buf, int ks) {
    int k0 = ks * BK;
    int t0 = wid * 2;  // chunk index, chunk = 16 rows
    const ushort* gA = cbf + (size_t)(r0 + t0*16 + lrow) * DIM + k0 + lk;
    async16(gA,            &Al[buf][t0*16][0]);
    async16(gA + 16*DIM,   &Al[buf][t0*16 + 16][0]);
    const ushort* gB = pbf + (size_t)(c0 + t0*16 + lrow) * DIM + k0 + lk;
    async16(gB,            &Bl[buf][t0*16][0]);
    async16(gB + 16*DIM,   &Bl[buf][t0*16 + 16][0]);
  };

  f32x4 acc[4][4];   // [n][m]
  #pragma unroll
  for (int n = 0; n < 4; ++n)
    #pragma unroll
    for (int m = 0; m < 4; ++m)
      acc[n][m] = (f32x4){0.f, 0.f, 0.f, 0.f};

  const int wr = wid >> 1, wc = wid & 1;   // 2x2 wave grid, 64x64 per wave
  const int rb = wr * 64, cbase = wc * 64;
  const int frow = lane & 15;
  const int fk = (((lane >> 4) ^ ((frow >> 1) & 3)) * 8);  // swizzled read

  stage(0, 0);
  #pragma unroll
  for (int ks = 0; ks < DIM / BK; ++ks) {
    __syncthreads();                       // staged tile ks is ready
    if (ks < DIM / BK - 1) stage((ks + 1) & 1, ks + 1);
    int buf = ks & 1;
    short8 af[4], bfr[4];
    #pragma unroll
    for (int m = 0; m < 4; ++m)
      af[m] = *(const short8*)&Al[buf][rb + m*16 + frow][fk];
    #pragma unroll
    for (int n = 0; n < 4; ++n)
      bfr[n] = *(const short8*)&Bl[buf][cbase + n*16 + frow][fk];
    // SWAPPED: A-operand = prev fragment, B-operand = curr fragment.
    // => D rows (lane>>4)*4+reg = prev col j, D cols lane&15 = curr row i.
    #pragma unroll
    for (int n = 0; n < 4; ++n)
      #pragma unroll
      for (int m = 0; m < 4; ++m)
        acc[n][m] = __builtin_amdgcn_mfma_f32_16x16x32_bf16(bfr[n], af[m], acc[n][m], 0, 0, 0);
  }

  // Epilogue: lane owns row i = rb + m*16 + (lane&15),
  //           cols j = cbase + n*16 + (lane>>4)*4 + r  (4 consecutive).
  float lp = 0.f;
  const int fi = lane & 15;
  const int g4 = (lane >> 4) << 2;
  #pragma unroll
  for (int m = 0; m < 4; ++m) {
    int il = rb + m*16 + fi;
    float4 rv = rowv[il];
    int rid = ridl[il];
    float* orow = out + (size_t)(r0 + il) * M_PREV + c0;
    #pragma unroll
    for (int n = 0; n < 4; ++n) {
      int jl0 = cbase + n*16 + g4;
      float4 res;
      #pragma unroll
      for (int r = 0; r < 4; ++r) {
        int jl = jl0 + r;
        float4 cv = colv[jl];
        float dot = acc[n][m][r];
        float cs = 1.0f - dot * rv.x * cv.x;
        float dx = rv.z - cv.z;
        float dy = rv.w - cv.w;
        float ccd = __builtin_amdgcn_sqrtf(dx*dx + dy*dy);
        (&res.x)[r] = 0.7f * cs + 0.3f * ccd;
        float d2 = fmaxf(rv.y + cv.y - 2.0f * dot, 0.0f);
        float dist = __builtin_amdgcn_sqrtf(d2);
        float tt = fmaxf(1.0f - dist, 0.0f);
        lp += (rid == cidl[jl]) ? d2 : tt * tt;
      }
      *(float4*)(orow + jl0) = res;
    }
  }

  #pragma unroll
  for (int m = 32; m; m >>= 1) lp += __shfl_xor(lp, m);
  if (lane == 0) wsum[wid] = lp;
  __syncthreads();
  if (tid == 0) partials[bid] = (wsum[0] + wsum[1]) + (wsum[2] + wsum[3]);
}

// Deterministic fixed-order reduction of block partials.
__global__ __launch_bounds__(256) void finalize_loss(
    const float* __restrict__ partials, float* __restrict__ loss_out)
{
  __shared__ float sh[4];
  float s = 0.f;
  for (int i = threadIdx.x; i < NBLK; i += 256) s += partials[i];
  #pragma unroll
  for (int m = 32; m; m >>= 1) s += __shfl_xor(s, m);
  if ((threadIdx.x & 63) == 0) sh[threadIdx.x >> 6] = s;
  __syncthreads();
  if (threadIdx.x == 0)
    loss_out[0] = ((sh[0] + sh[1]) + (sh[2] + sh[3])) * (1.0f / 41943040.0f);
}

extern "C" void kernel_launch(void* const* d_in, const int* in_sizes, int n_in,
                              void* d_out, int out_size, void* d_ws, size_t ws_size,
                              hipStream_t stream) {
  const float* ce  = (const float*)d_in[0];
  const float* cbx = (const float*)d_in[1];
  const float* pe  = (const float*)d_in[2];
  const float* pbx = (const float*)d_in[3];
  const int*   cid = (const int*)d_in[4];
  const int*   pid = (const int*)d_in[5];
  float* out = (float*)d_out;

  char* ws = (char*)d_ws;
  ushort* cbf = (ushort*)ws;                        // 4096*256*2  = 2 MB
  ushort* pbf = (ushort*)(ws + (2u << 20));         // 10240*256*2 = 5 MB
  float4* cpar = (float4*)(ws + 7340032);           // 64 KB
  float4* ppar = (float4*)(ws + 7340032 + 65536);   // 160 KB
  float* partials = (float*)(ws + 7340032 + 65536 + 163840);  // 10 KB

  prep_kernel<<<(N_CURR + M_PREV) / 4, 256, 0, stream>>>(
      ce, cbx, pe, pbx, cbf, pbf, cpar, ppar);
  main_kernel<<<NBLK, 256, 0, stream>>>(
      cbf, pbf, cpar, ppar, cid, pid, out, partials);
  finalize_loss<<<1, 256, 0, stream>>>(partials, out + (size_t)N_CURR * M_PREV);
}